// Round 20
// baseline (343.754 us; speedup 1.0000x reference)
//
#include <hip/hip_runtime.h>
#include <hip/hip_fp16.h>
#include <math.h>

static constexpr int D = 64;     // hidden dim
static constexpr int F = 128;    // input features
static constexpr int BK = 64;    // bucket capacity per node (real edges; P(ovf)~1e-17)
static constexpr float NEG_SLOPE = 0.2f;
static constexpr float LN_EPS = 1e-5f;
static constexpr float LOG2E = 1.44269504088896340736f;
static constexpr int NCHUNK = 8;     // dst-range chunks (== NXCD)

// ---- DPP cross-lane reduction helpers (no LDS traffic) ----
template <int CTRL>
__device__ __forceinline__ float dpp_add(float x) {
  int v = __builtin_amdgcn_update_dpp(0, __float_as_int(x), CTRL, 0xF, 0xF, true);
  return x + __int_as_float(v);
}
// sum within each aligned 4-lane group (replicated)
__device__ __forceinline__ float red4(float x) {
  x = dpp_add<0xB1>(x);    // quad_perm xor 1
  x = dpp_add<0x4E>(x);    // quad_perm xor 2
  return x;
}
// sum within each aligned 16-lane group (replicated)
__device__ __forceinline__ float red16(float x) {
  x = red4(x);
  x = dpp_add<0x141>(x);   // row_half_mirror
  x = dpp_add<0x140>(x);   // row_mirror
  return x;
}

// ---- packed fp16 helpers ----
__device__ __forceinline__ __half2 h2max(__half2 a, __half2 b) {
  int ai = __builtin_bit_cast(int, a), bi = __builtin_bit_cast(int, b), r;
  asm("v_pk_max_f16 %0, %1, %2" : "=v"(r) : "v"(ai), "v"(bi));
  return __builtin_bit_cast(__half2, r);
}

typedef _Float16 half2_t __attribute__((ext_vector_type(2)));
__device__ __forceinline__ float fdot2f(__half2 a, __half2 b, float c) {
#if __has_builtin(__builtin_amdgcn_fdot2)
  return __builtin_amdgcn_fdot2(__builtin_bit_cast(half2_t, a),
                                __builtin_bit_cast(half2_t, b), c, false);
#else
  float2 af = __half22float2(a), bf = __half22float2(b);
  return fmaf(af.x, bf.x, fmaf(af.y, bf.y, c));
#endif
}

// ---------------- bucket CSR build ----------------
// No table init: masked slots clamp their index to the node's own row, so
// garbage entries are loaded-then-discarded. Self-loop is virtual (computed
// in the edge kernel). Cursor zeroed via hipMemsetAsync.

// SE-model XCD pinning probe: hypothesis XCD = (blockIdx%32)>>2 (round-robin
// over 32 shader engines, 4 SEs per XCD). Chunk c gets blocks with
// (blockIdx>>2)&7 == c, i.e. blockIdx%32 in {4c..4c+3} -> ONE XCD if the
// SE model holds. Worker id = (blockIdx>>5)*4 + (blockIdx&3).
__global__ __launch_bounds__(256) void k_scatter(const int* __restrict__ src,
                                                 const int* __restrict__ dst,
                                                 int* __restrict__ cursor,
                                                 int* __restrict__ ssrc, int E, int N) {
  int c = (blockIdx.x >> 2) & (NCHUNK - 1);
  int b0 = (c * N) / NCHUNK, b1 = ((c + 1) * N) / NCHUNK;
  int worker = ((blockIdx.x >> 5) << 2) | (blockIdx.x & 3);   // 0..255
  int stride = (gridDim.x / NCHUNK) * 256;
  for (int e = worker * 256 + threadIdx.x; e < E; e += stride) {
    int d = dst[e];
    if (d >= b0 && d < b1) {
      int p = atomicAdd(&cursor[d], 1);
      if (p < BK) ssrc[(d << 6) + p] = src[e];   // overflow guard (never fires)
    }
  }
}

// ---------------- encoder: h = relu(x @ W_enc + b_enc), tiled ----------------

__global__ __launch_bounds__(256) void k_encoder(const float* __restrict__ x,
                                                 const float* __restrict__ W,
                                                 const float* __restrict__ b,
                                                 float* __restrict__ h, int N) {
  __shared__ float xT[F][64];   // 32 KiB, k-major
  __shared__ float Ws[F][64];   // 32 KiB, [k][c]
  int t = threadIdx.x;
  int n0 = blockIdx.x * 64;
  for (int i = t; i < F * D / 4; i += 256)
    ((float4*)&Ws[0][0])[i] = ((const float4*)W)[i];
  {
    int r = t & 63, kq = (t >> 6) * 4;
    int n = n0 + r;
#pragma unroll
    for (int i = 0; i < 8; ++i) {
      int k0 = kq + 16 * i;
      float4 v = (n < N) ? *(const float4*)&x[(size_t)n * F + k0]
                         : make_float4(0.f, 0.f, 0.f, 0.f);
      xT[k0][r] = v.x; xT[k0 + 1][r] = v.y; xT[k0 + 2][r] = v.z; xT[k0 + 3][r] = v.w;
    }
  }
  __syncthreads();
  int c4 = (t & 15) * 4, n4 = (t >> 4) * 4;
  float acc[4][4];
#pragma unroll
  for (int i = 0; i < 4; ++i)
#pragma unroll
    for (int j = 0; j < 4; ++j) acc[i][j] = b[c4 + j];
#pragma unroll 4
  for (int k = 0; k < F; ++k) {
    float4 xv = *(const float4*)&xT[k][n4];
    float4 wv = *(const float4*)&Ws[k][c4];
    const float* xp = (const float*)&xv;
    const float* wp = (const float*)&wv;
#pragma unroll
    for (int i = 0; i < 4; ++i)
#pragma unroll
      for (int j = 0; j < 4; ++j) acc[i][j] = fmaf(xp[i], wp[j], acc[i][j]);
  }
#pragma unroll
  for (int i = 0; i < 4; ++i) {
    int n = n0 + n4 + i;
    if (n < N) {
      float4 o = make_float4(fmaxf(acc[i][0], 0.f), fmaxf(acc[i][1], 0.f),
                             fmaxf(acc[i][2], 0.f), fmaxf(acc[i][3], 0.f));
      *(float4*)&h[(size_t)n * D + c4] = o;
    }
  }
}

// ---------------- per-layer projections: xl(fp16) = h@Wl+bl, xr(f32) = h@Wr+br ----------------

__global__ __launch_bounds__(256) void k_layer_gemm(const float* __restrict__ h,
                                                    const float* __restrict__ Wl,
                                                    const float* __restrict__ bl,
                                                    const float* __restrict__ Wr,
                                                    const float* __restrict__ br,
                                                    ushort* __restrict__ xlh,
                                                    float* __restrict__ xr, int N) {
  __shared__ float hT[D][64];    // 16 KiB, k-major
  __shared__ float Wls[D][64];   // 16 KiB
  __shared__ float Wrs[D][64];   // 16 KiB
  int t = threadIdx.x;
  int n0 = blockIdx.x * 64;
  for (int i = t; i < D * D / 4; i += 256) {
    ((float4*)&Wls[0][0])[i] = ((const float4*)Wl)[i];
    ((float4*)&Wrs[0][0])[i] = ((const float4*)Wr)[i];
  }
  {
    int r = t & 63, kq = (t >> 6) * 4;
    int n = n0 + r;
#pragma unroll
    for (int i = 0; i < 4; ++i) {
      int k0 = kq + 16 * i;
      float4 v = (n < N) ? *(const float4*)&h[(size_t)n * D + k0]
                         : make_float4(0.f, 0.f, 0.f, 0.f);
      hT[k0][r] = v.x; hT[k0 + 1][r] = v.y; hT[k0 + 2][r] = v.z; hT[k0 + 3][r] = v.w;
    }
  }
  __syncthreads();
  int c4 = (t & 15) * 4, n4 = (t >> 4) * 4;
  float aL[4][4], aR[4][4];
#pragma unroll
  for (int i = 0; i < 4; ++i)
#pragma unroll
    for (int j = 0; j < 4; ++j) { aL[i][j] = bl[c4 + j]; aR[i][j] = br[c4 + j]; }
#pragma unroll 4
  for (int k = 0; k < D; ++k) {
    float4 xv = *(const float4*)&hT[k][n4];
    float4 lv = *(const float4*)&Wls[k][c4];
    float4 rv = *(const float4*)&Wrs[k][c4];
    const float* xp = (const float*)&xv;
    const float* lp = (const float*)&lv;
    const float* rp = (const float*)&rv;
#pragma unroll
    for (int i = 0; i < 4; ++i)
#pragma unroll
      for (int j = 0; j < 4; ++j) {
        aL[i][j] = fmaf(xp[i], lp[j], aL[i][j]);
        aR[i][j] = fmaf(xp[i], rp[j], aR[i][j]);
      }
  }
#pragma unroll
  for (int i = 0; i < 4; ++i) {
    int n = n0 + n4 + i;
    if (n < N) {
      ushort4 o;
      o.x = __half_as_ushort(__float2half_rn(aL[i][0]));
      o.y = __half_as_ushort(__float2half_rn(aL[i][1]));
      o.z = __half_as_ushort(__float2half_rn(aL[i][2]));
      o.w = __half_as_ushort(__float2half_rn(aL[i][3]));
      *(ushort4*)&xlh[(size_t)n * D + c4] = o;
      *(float4*)&xr[(size_t)n * D + c4] =
          make_float4(aR[i][0], aR[i][1], aR[i][2], aR[i][3]);
    }
  }
}

// ---------------- edge + softmax + aggregate + LN + ELU ----------------
// QUARTER-PER-NODE (R19, unchanged): each 16-lane quarter owns one node;
// four gather chains in flight per wave by construction.

struct Q4 { float x, y, z, w; };

template <int P>
__device__ __forceinline__ void batchQ(const char* __restrict__ xlb,
                                       const int* __restrict__ srow,
                                       int slot0, int cnt, int voff, int nd,
                                       __half2 xr_lo, __half2 xr_hi,
                                       __half2 a_lo, __half2 a_hi, __half2 ns2,
                                       float& m, float& s, Q4& acc) {
  int sj[P];
#pragma unroll
  for (int g = 0; g < P / 4; ++g) {
    int4 q = *(const int4*)(srow + slot0 + 4 * g);
    sj[4 * g + 0] = q.x; sj[4 * g + 1] = q.y;
    sj[4 * g + 2] = q.z; sj[4 * g + 3] = q.w;
  }
#pragma unroll
  for (int j = 0; j < P; ++j)
    if (slot0 + j >= cnt) sj[j] = nd;   // clamp garbage/unused slots to own row
  uint2 xsv[P];
  float p[P];
#pragma unroll
  for (int j = 0; j < P; ++j)
    xsv[j] = *(const uint2*)(xlb + (((uint32_t)sj[j] << 7) | (uint32_t)voff));
#pragma unroll
  for (int j = 0; j < P; ++j) {
    __half2 lo = __builtin_bit_cast(__half2, xsv[j].x);
    __half2 hi = __builtin_bit_cast(__half2, xsv[j].y);
    __half2 vlo = __hadd2(lo, xr_lo), vhi = __hadd2(hi, xr_hi);
    __half2 llo = h2max(vlo, __hmul2(vlo, ns2));   // leaky, exact for slope<1
    __half2 lhi = h2max(vhi, __hmul2(vhi, ns2));
    float d = red4(fdot2f(a_hi, lhi, fdot2f(a_lo, llo, 0.f)));
    p[j] = (slot0 + j < cnt) ? d : -3.0e38f;
  }
  float pmax = p[0];
#pragma unroll
  for (int j = 1; j < P; ++j) pmax = fmaxf(pmax, p[j]);
  float mnew = fmaxf(m, pmax);
  float c = __builtin_amdgcn_exp2f(m - mnew);
  s *= c; acc.x *= c; acc.y *= c; acc.z *= c; acc.w *= c;
#pragma unroll
  for (int j = 0; j < P; ++j) {
    float w = __builtin_amdgcn_exp2f(p[j] - mnew);
    s += w;
    __half2 lo = __builtin_bit_cast(__half2, xsv[j].x);
    __half2 hi = __builtin_bit_cast(__half2, xsv[j].y);
    acc.x = fmaf(w, __low2float(lo), acc.x);
    acc.y = fmaf(w, __high2float(lo), acc.y);
    acc.z = fmaf(w, __low2float(hi), acc.z);
    acc.w = fmaf(w, __high2float(hi), acc.w);
  }
  m = mnew;
}

__global__ __launch_bounds__(256) void k_edge_layer(const __half* __restrict__ xlh,
                                                    const float* __restrict__ xr,
                                                    const int* __restrict__ cnt_arr,
                                                    const int* __restrict__ ssrc,
                                                    const float* __restrict__ att_l,
                                                    const float* __restrict__ ob_l,
                                                    const float* __restrict__ g_l,
                                                    const float* __restrict__ be_l,
                                                    float* __restrict__ out, int N) {
  int lane = threadIdx.x & 63;
  int c4l = lane & 15, quad = lane >> 4;
  int voff = c4l * 8;              // 4 channels x 2B
  int wid = threadIdx.x >> 6;
  int wave = blockIdx.x * 4 + wid;
  int nw = gridDim.x * 4;
  const char* xlb = (const char*)xlh;
  float4 af = *(const float4*)&att_l[4 * c4l];
  __half2 a_lo = __float22half2_rn(make_float2(af.x * LOG2E, af.y * LOG2E));
  __half2 a_hi = __float22half2_rn(make_float2(af.z * LOG2E, af.w * LOG2E));
  __half2 ns2 = __float2half2_rn(NEG_SLOPE);
  float4 ob = *(const float4*)&ob_l[4 * c4l];
  float4 gm = *(const float4*)&g_l[4 * c4l];
  float4 bt = *(const float4*)&be_l[4 * c4l];
  int nquads = (N + 3) >> 2;
  for (int ip = wave; ip < nquads; ip += nw) {
    int node = 4 * ip + quad;
    bool valid = node < N;
    int nd = valid ? node : N - 1;   // safe for loads; write gated
    float4 xrf = *(const float4*)&xr[(size_t)nd * D + 4 * c4l];
    __half2 xr_lo = __float22half2_rn(make_float2(xrf.x, xrf.y));
    __half2 xr_hi = __float22half2_rn(make_float2(xrf.z, xrf.w));
    int cnt = min(cnt_arr[nd], BK);  // REAL edges only (self-loop virtual)
    const int* srow = ssrc + (nd << 6);
    // virtual self-loop: own row, weight 2^0 = 1
    uint2 xss = *(const uint2*)(xlb + (((uint32_t)nd << 7) | (uint32_t)voff));
    __half2 slo = __builtin_bit_cast(__half2, xss.x);
    __half2 shi = __builtin_bit_cast(__half2, xss.y);
    __half2 vlo = __hadd2(slo, xr_lo), vhi = __hadd2(shi, xr_hi);
    __half2 llo = h2max(vlo, __hmul2(vlo, ns2));
    __half2 lhi = h2max(vhi, __hmul2(vhi, ns2));
    float m = red4(fdot2f(a_hi, lhi, fdot2f(a_lo, llo, 0.f)));
    float s = 1.f;
    Q4 acc{__low2float(slo), __high2float(slo), __low2float(shi), __high2float(shi)};
    if (cnt > 0)
      batchQ<16>(xlb, srow, 0, cnt, voff, nd, xr_lo, xr_hi, a_lo, a_hi, ns2, m, s, acc);
    for (int slot = 16; slot < cnt; slot += 4)
      batchQ<4>(xlb, srow, slot, cnt, voff, nd, xr_lo, xr_hi, a_lo, a_hi, ns2, m, s, acc);
    // epilogue: finalize softmax, LayerNorm over the quarter's 64 channels, ELU
    float rs = __builtin_amdgcn_rcpf(s);
    float r0 = fmaf(acc.x, rs, ob.x);
    float r1 = fmaf(acc.y, rs, ob.y);
    float r2 = fmaf(acc.z, rs, ob.z);
    float r3 = fmaf(acc.w, rs, ob.w);
    float mu = red16(r0 + r1 + r2 + r3) * (1.f / 64.f);
    float d0 = r0 - mu, d1 = r1 - mu, d2 = r2 - mu, d3 = r3 - mu;
    float var = red16(fmaf(d0, d0, fmaf(d1, d1, fmaf(d2, d2, d3 * d3)))) * (1.f / 64.f);
    float rstd = rsqrtf(var + LN_EPS);
    float h0 = fmaf(d0 * rstd, gm.x, bt.x);
    float h1 = fmaf(d1 * rstd, gm.y, bt.y);
    float h2 = fmaf(d2 * rstd, gm.z, bt.z);
    float h3 = fmaf(d3 * rstd, gm.w, bt.w);
    h0 = h0 > 0.f ? h0 : expm1f(h0);
    h1 = h1 > 0.f ? h1 : expm1f(h1);
    h2 = h2 > 0.f ? h2 : expm1f(h2);
    h3 = h3 > 0.f ? h3 : expm1f(h3);
    if (valid)
      *(float4*)&out[(size_t)node * D + 4 * c4l] = make_float4(h0, h1, h2, h3);
  }
}

// ---------------- launch ----------------

extern "C" void kernel_launch(void* const* d_in, const int* in_sizes, int n_in,
                              void* d_out, int out_size, void* d_ws, size_t ws_size,
                              hipStream_t stream) {
  const float* x      = (const float*)d_in[0];
  const int*   ei     = (const int*)d_in[1];
  const float* W_enc  = (const float*)d_in[2];
  const float* b_enc  = (const float*)d_in[3];
  const float* Wl     = (const float*)d_in[4];
  const float* bl     = (const float*)d_in[5];
  const float* Wr     = (const float*)d_in[6];
  const float* br     = (const float*)d_in[7];
  const float* att    = (const float*)d_in[8];
  const float* obias  = (const float*)d_in[9];
  const float* gamma  = (const float*)d_in[10];
  const float* beta   = (const float*)d_in[11];

  int N = in_sizes[0] / F;       // 100000
  int E = in_sizes[1] / 2;       // 1600000
  const int* src = ei;
  const int* dst = ei + E;

  auto align = [](size_t v) { return (v + 255) & ~(size_t)255; };
  char* ws = (char*)d_ws;
  float* h  = (float*)ws;   ws += align((size_t)N * D * 4);
  ushort* xlh = (ushort*)ws; ws += align((size_t)N * D * 2);
  float* xr = (float*)ws;   ws += align((size_t)N * D * 4);
  int* cursor = (int*)ws;   ws += align((size_t)N * 4);
  int* ssrc   = (int*)ws;   ws += align(((size_t)N * BK + 16) * 4);

  int tblk = (N + 63) / 64;

  // CSR build: zero cursors (async memset), scatter into uninitialized buckets
  hipMemsetAsync(cursor, 0, (size_t)N * 4, stream);
  k_scatter<<<2048, 256, 0, stream>>>(src, dst, cursor, ssrc, E, N);

  // encoder
  k_encoder<<<tblk, 256, 0, stream>>>(x, W_enc, b_enc, h, N);

  for (int l = 0; l < 3; ++l) {
    k_layer_gemm<<<tblk, 256, 0, stream>>>(h, Wl + l * D * D, bl + l * D,
                                           Wr + l * D * D, br + l * D, xlh, xr, N);
    float* out = (l == 2) ? (float*)d_out : h;
    k_edge_layer<<<2048, 256, 0, stream>>>((const __half*)xlh, xr, cursor, ssrc,
                                           att + l * 64, obias + l * 64,
                                           gamma + l * 64, beta + l * 64, out, N);
  }
}

// Round 21
// 330.968 us; speedup vs baseline: 1.0386x; 1.0386x over previous
//
#include <hip/hip_runtime.h>
#include <hip/hip_fp16.h>
#include <math.h>

static constexpr int D = 64;     // hidden dim
static constexpr int F = 128;    // input features
static constexpr int BK = 64;    // bucket capacity per node (real edges; P(ovf)~1e-17)
static constexpr float NEG_SLOPE = 0.2f;
static constexpr float LN_EPS = 1e-5f;
static constexpr float LOG2E = 1.44269504088896340736f;
static constexpr int NCHUNK = 8;     // dst-range chunks (== NXCD)

// ---- DPP cross-lane reduction helpers (no LDS traffic) ----
template <int CTRL>
__device__ __forceinline__ float dpp_add(float x) {
  int v = __builtin_amdgcn_update_dpp(0, __float_as_int(x), CTRL, 0xF, 0xF, true);
  return x + __int_as_float(v);
}
// sum within each aligned 4-lane group (replicated)
__device__ __forceinline__ float red4(float x) {
  x = dpp_add<0xB1>(x);    // quad_perm xor 1
  x = dpp_add<0x4E>(x);    // quad_perm xor 2
  return x;
}
// sum within each aligned 16-lane group (replicated)
__device__ __forceinline__ float red16(float x) {
  x = red4(x);
  x = dpp_add<0x141>(x);   // row_half_mirror
  x = dpp_add<0x140>(x);   // row_mirror
  return x;
}

// ---- packed fp16 helpers ----
__device__ __forceinline__ __half2 h2max(__half2 a, __half2 b) {
  int ai = __builtin_bit_cast(int, a), bi = __builtin_bit_cast(int, b), r;
  asm("v_pk_max_f16 %0, %1, %2" : "=v"(r) : "v"(ai), "v"(bi));
  return __builtin_bit_cast(__half2, r);
}

typedef _Float16 half2_t __attribute__((ext_vector_type(2)));
__device__ __forceinline__ float fdot2f(__half2 a, __half2 b, float c) {
#if __has_builtin(__builtin_amdgcn_fdot2)
  return __builtin_amdgcn_fdot2(__builtin_bit_cast(half2_t, a),
                                __builtin_bit_cast(half2_t, b), c, false);
#else
  float2 af = __half22float2(a), bf = __half22float2(b);
  return fmaf(af.x, bf.x, fmaf(af.y, bf.y, c));
#endif
}

// ---------------- bucket CSR build ----------------
// No table init: masked slots clamp their index to the node's own row, so
// garbage entries are loaded-then-discarded. Self-loop is virtual (computed
// in the edge kernel). Cursor zeroed via hipMemsetAsync.
// R19 scatter form (best measured across 5 variants; ~72us = atomic floor).

__global__ __launch_bounds__(256) void k_scatter(const int* __restrict__ src,
                                                 const int* __restrict__ dst,
                                                 int* __restrict__ cursor,
                                                 int* __restrict__ ssrc, int E, int N) {
  int c = blockIdx.x & (NCHUNK - 1);
  int b0 = (c * N) / NCHUNK, b1 = ((c + 1) * N) / NCHUNK;
  int stride = (gridDim.x / NCHUNK) * 256;
  for (int e = (blockIdx.x >> 3) * 256 + threadIdx.x; e < E; e += stride) {
    int d = dst[e];
    if (d >= b0 && d < b1) {
      int p = atomicAdd(&cursor[d], 1);
      if (p < BK) ssrc[(d << 6) + p] = src[e];   // overflow guard (never fires)
    }
  }
}

// ---------------- encoder: h = relu(x @ W_enc + b_enc), tiled ----------------

__global__ __launch_bounds__(256) void k_encoder(const float* __restrict__ x,
                                                 const float* __restrict__ W,
                                                 const float* __restrict__ b,
                                                 float* __restrict__ h, int N) {
  __shared__ float xT[F][64];   // 32 KiB, k-major
  __shared__ float Ws[F][64];   // 32 KiB, [k][c]
  int t = threadIdx.x;
  int n0 = blockIdx.x * 64;
  for (int i = t; i < F * D / 4; i += 256)
    ((float4*)&Ws[0][0])[i] = ((const float4*)W)[i];
  {
    int r = t & 63, kq = (t >> 6) * 4;
    int n = n0 + r;
#pragma unroll
    for (int i = 0; i < 8; ++i) {
      int k0 = kq + 16 * i;
      float4 v = (n < N) ? *(const float4*)&x[(size_t)n * F + k0]
                         : make_float4(0.f, 0.f, 0.f, 0.f);
      xT[k0][r] = v.x; xT[k0 + 1][r] = v.y; xT[k0 + 2][r] = v.z; xT[k0 + 3][r] = v.w;
    }
  }
  __syncthreads();
  int c4 = (t & 15) * 4, n4 = (t >> 4) * 4;
  float acc[4][4];
#pragma unroll
  for (int i = 0; i < 4; ++i)
#pragma unroll
    for (int j = 0; j < 4; ++j) acc[i][j] = b[c4 + j];
#pragma unroll 4
  for (int k = 0; k < F; ++k) {
    float4 xv = *(const float4*)&xT[k][n4];
    float4 wv = *(const float4*)&Ws[k][c4];
    const float* xp = (const float*)&xv;
    const float* wp = (const float*)&wv;
#pragma unroll
    for (int i = 0; i < 4; ++i)
#pragma unroll
      for (int j = 0; j < 4; ++j) acc[i][j] = fmaf(xp[i], wp[j], acc[i][j]);
  }
#pragma unroll
  for (int i = 0; i < 4; ++i) {
    int n = n0 + n4 + i;
    if (n < N) {
      float4 o = make_float4(fmaxf(acc[i][0], 0.f), fmaxf(acc[i][1], 0.f),
                             fmaxf(acc[i][2], 0.f), fmaxf(acc[i][3], 0.f));
      *(float4*)&h[(size_t)n * D + c4] = o;
    }
  }
}

// ---------------- per-layer projections: xl(fp16) = h@Wl+bl, xr(f32) = h@Wr+br ----------------

__global__ __launch_bounds__(256) void k_layer_gemm(const float* __restrict__ h,
                                                    const float* __restrict__ Wl,
                                                    const float* __restrict__ bl,
                                                    const float* __restrict__ Wr,
                                                    const float* __restrict__ br,
                                                    ushort* __restrict__ xlh,
                                                    float* __restrict__ xr, int N) {
  __shared__ float hT[D][64];    // 16 KiB, k-major
  __shared__ float Wls[D][64];   // 16 KiB
  __shared__ float Wrs[D][64];   // 16 KiB
  int t = threadIdx.x;
  int n0 = blockIdx.x * 64;
  for (int i = t; i < D * D / 4; i += 256) {
    ((float4*)&Wls[0][0])[i] = ((const float4*)Wl)[i];
    ((float4*)&Wrs[0][0])[i] = ((const float4*)Wr)[i];
  }
  {
    int r = t & 63, kq = (t >> 6) * 4;
    int n = n0 + r;
#pragma unroll
    for (int i = 0; i < 4; ++i) {
      int k0 = kq + 16 * i;
      float4 v = (n < N) ? *(const float4*)&h[(size_t)n * D + k0]
                         : make_float4(0.f, 0.f, 0.f, 0.f);
      hT[k0][r] = v.x; hT[k0 + 1][r] = v.y; hT[k0 + 2][r] = v.z; hT[k0 + 3][r] = v.w;
    }
  }
  __syncthreads();
  int c4 = (t & 15) * 4, n4 = (t >> 4) * 4;
  float aL[4][4], aR[4][4];
#pragma unroll
  for (int i = 0; i < 4; ++i)
#pragma unroll
    for (int j = 0; j < 4; ++j) { aL[i][j] = bl[c4 + j]; aR[i][j] = br[c4 + j]; }
#pragma unroll 4
  for (int k = 0; k < D; ++k) {
    float4 xv = *(const float4*)&hT[k][n4];
    float4 lv = *(const float4*)&Wls[k][c4];
    float4 rv = *(const float4*)&Wrs[k][c4];
    const float* xp = (const float*)&xv;
    const float* lp = (const float*)&lv;
    const float* rp = (const float*)&rv;
#pragma unroll
    for (int i = 0; i < 4; ++i)
#pragma unroll
      for (int j = 0; j < 4; ++j) {
        aL[i][j] = fmaf(xp[i], lp[j], aL[i][j]);
        aR[i][j] = fmaf(xp[i], rp[j], aR[i][j]);
      }
  }
#pragma unroll
  for (int i = 0; i < 4; ++i) {
    int n = n0 + n4 + i;
    if (n < N) {
      ushort4 o;
      o.x = __half_as_ushort(__float2half_rn(aL[i][0]));
      o.y = __half_as_ushort(__float2half_rn(aL[i][1]));
      o.z = __half_as_ushort(__float2half_rn(aL[i][2]));
      o.w = __half_as_ushort(__float2half_rn(aL[i][3]));
      *(ushort4*)&xlh[(size_t)n * D + c4] = o;
      *(float4*)&xr[(size_t)n * D + c4] =
          make_float4(aR[i][0], aR[i][1], aR[i][2], aR[i][3]);
    }
  }
}

// ---------------- edge + softmax + aggregate + LN + ELU ----------------
// QUARTER-PER-NODE (R19): each 16-lane quarter owns one node; four gather
// chains in flight per wave. NO online max: inputs are LN-bounded so log2
// scores are far from f32 exp2 range limits -> direct w = 2^p accumulation
// (removes pmax tree + rescale + the serial batch-merge dependency).

struct Q4 { float x, y, z, w; };

template <int P>
__device__ __forceinline__ void batchQ(const char* __restrict__ xlb,
                                       const int* __restrict__ srow,
                                       int slot0, int cnt, int voff, int nd,
                                       __half2 xr_lo, __half2 xr_hi,
                                       __half2 a_lo, __half2 a_hi, __half2 ns2,
                                       float& s, Q4& acc) {
  int sj[P];
#pragma unroll
  for (int g = 0; g < P / 4; ++g) {
    int4 q = *(const int4*)(srow + slot0 + 4 * g);
    sj[4 * g + 0] = q.x; sj[4 * g + 1] = q.y;
    sj[4 * g + 2] = q.z; sj[4 * g + 3] = q.w;
  }
#pragma unroll
  for (int j = 0; j < P; ++j)
    if (slot0 + j >= cnt) sj[j] = nd;   // clamp garbage/unused slots to own row
  uint2 xsv[P];
  float w[P];
#pragma unroll
  for (int j = 0; j < P; ++j)
    xsv[j] = *(const uint2*)(xlb + (((uint32_t)sj[j] << 7) | (uint32_t)voff));
#pragma unroll
  for (int j = 0; j < P; ++j) {
    __half2 lo = __builtin_bit_cast(__half2, xsv[j].x);
    __half2 hi = __builtin_bit_cast(__half2, xsv[j].y);
    __half2 vlo = __hadd2(lo, xr_lo), vhi = __hadd2(hi, xr_hi);
    __half2 llo = h2max(vlo, __hmul2(vlo, ns2));   // leaky, exact for slope<1
    __half2 lhi = h2max(vhi, __hmul2(vhi, ns2));
    float d = red4(fdot2f(a_hi, lhi, fdot2f(a_lo, llo, 0.f)));
    float wj = __builtin_amdgcn_exp2f(d);
    w[j] = (slot0 + j < cnt) ? wj : 0.f;
  }
#pragma unroll
  for (int j = 0; j < P; ++j) {
    s += w[j];
    __half2 lo = __builtin_bit_cast(__half2, xsv[j].x);
    __half2 hi = __builtin_bit_cast(__half2, xsv[j].y);
    acc.x = fmaf(w[j], __low2float(lo), acc.x);
    acc.y = fmaf(w[j], __high2float(lo), acc.y);
    acc.z = fmaf(w[j], __low2float(hi), acc.z);
    acc.w = fmaf(w[j], __high2float(hi), acc.w);
  }
}

__global__ __launch_bounds__(256) void k_edge_layer(const __half* __restrict__ xlh,
                                                    const float* __restrict__ xr,
                                                    const int* __restrict__ cnt_arr,
                                                    const int* __restrict__ ssrc,
                                                    const float* __restrict__ att_l,
                                                    const float* __restrict__ ob_l,
                                                    const float* __restrict__ g_l,
                                                    const float* __restrict__ be_l,
                                                    float* __restrict__ out, int N) {
  int lane = threadIdx.x & 63;
  int c4l = lane & 15, quad = lane >> 4;
  int voff = c4l * 8;              // 4 channels x 2B
  int wid = threadIdx.x >> 6;
  int wave = blockIdx.x * 4 + wid;
  int nw = gridDim.x * 4;
  const char* xlb = (const char*)xlh;
  float4 af = *(const float4*)&att_l[4 * c4l];
  __half2 a_lo = __float22half2_rn(make_float2(af.x * LOG2E, af.y * LOG2E));
  __half2 a_hi = __float22half2_rn(make_float2(af.z * LOG2E, af.w * LOG2E));
  __half2 ns2 = __float2half2_rn(NEG_SLOPE);
  float4 ob = *(const float4*)&ob_l[4 * c4l];
  float4 gm = *(const float4*)&g_l[4 * c4l];
  float4 bt = *(const float4*)&be_l[4 * c4l];
  int nquads = (N + 3) >> 2;
  for (int ip = wave; ip < nquads; ip += nw) {
    int node = 4 * ip + quad;
    bool valid = node < N;
    int nd = valid ? node : N - 1;   // safe for loads; write gated
    float4 xrf = *(const float4*)&xr[(size_t)nd * D + 4 * c4l];
    __half2 xr_lo = __float22half2_rn(make_float2(xrf.x, xrf.y));
    __half2 xr_hi = __float22half2_rn(make_float2(xrf.z, xrf.w));
    int cnt = min(cnt_arr[nd], BK);  // REAL edges only (self-loop virtual)
    const int* srow = ssrc + (nd << 6);
    // virtual self-loop: own row, direct weight 2^p_self
    uint2 xss = *(const uint2*)(xlb + (((uint32_t)nd << 7) | (uint32_t)voff));
    __half2 slo = __builtin_bit_cast(__half2, xss.x);
    __half2 shi = __builtin_bit_cast(__half2, xss.y);
    __half2 vlo = __hadd2(slo, xr_lo), vhi = __hadd2(shi, xr_hi);
    __half2 llo = h2max(vlo, __hmul2(vlo, ns2));
    __half2 lhi = h2max(vhi, __hmul2(vhi, ns2));
    float w0 = __builtin_amdgcn_exp2f(red4(fdot2f(a_hi, lhi, fdot2f(a_lo, llo, 0.f))));
    float s = w0;
    Q4 acc{w0 * __low2float(slo), w0 * __high2float(slo),
           w0 * __low2float(shi), w0 * __high2float(shi)};
    if (cnt > 0)
      batchQ<16>(xlb, srow, 0, cnt, voff, nd, xr_lo, xr_hi, a_lo, a_hi, ns2, s, acc);
    for (int slot = 16; slot < cnt; slot += 4)
      batchQ<4>(xlb, srow, slot, cnt, voff, nd, xr_lo, xr_hi, a_lo, a_hi, ns2, s, acc);
    // epilogue: finalize softmax, LayerNorm over the quarter's 64 channels, ELU
    float rs = __builtin_amdgcn_rcpf(s);
    float r0 = fmaf(acc.x, rs, ob.x);
    float r1 = fmaf(acc.y, rs, ob.y);
    float r2 = fmaf(acc.z, rs, ob.z);
    float r3 = fmaf(acc.w, rs, ob.w);
    float mu = red16(r0 + r1 + r2 + r3) * (1.f / 64.f);
    float d0 = r0 - mu, d1 = r1 - mu, d2 = r2 - mu, d3 = r3 - mu;
    float var = red16(fmaf(d0, d0, fmaf(d1, d1, fmaf(d2, d2, d3 * d3)))) * (1.f / 64.f);
    float rstd = rsqrtf(var + LN_EPS);
    float h0 = fmaf(d0 * rstd, gm.x, bt.x);
    float h1 = fmaf(d1 * rstd, gm.y, bt.y);
    float h2 = fmaf(d2 * rstd, gm.z, bt.z);
    float h3 = fmaf(d3 * rstd, gm.w, bt.w);
    h0 = h0 > 0.f ? h0 : expm1f(h0);
    h1 = h1 > 0.f ? h1 : expm1f(h1);
    h2 = h2 > 0.f ? h2 : expm1f(h2);
    h3 = h3 > 0.f ? h3 : expm1f(h3);
    if (valid)
      *(float4*)&out[(size_t)node * D + 4 * c4l] = make_float4(h0, h1, h2, h3);
  }
}

// ---------------- launch ----------------

extern "C" void kernel_launch(void* const* d_in, const int* in_sizes, int n_in,
                              void* d_out, int out_size, void* d_ws, size_t ws_size,
                              hipStream_t stream) {
  const float* x      = (const float*)d_in[0];
  const int*   ei     = (const int*)d_in[1];
  const float* W_enc  = (const float*)d_in[2];
  const float* b_enc  = (const float*)d_in[3];
  const float* Wl     = (const float*)d_in[4];
  const float* bl     = (const float*)d_in[5];
  const float* Wr     = (const float*)d_in[6];
  const float* br     = (const float*)d_in[7];
  const float* att    = (const float*)d_in[8];
  const float* obias  = (const float*)d_in[9];
  const float* gamma  = (const float*)d_in[10];
  const float* beta   = (const float*)d_in[11];

  int N = in_sizes[0] / F;       // 100000
  int E = in_sizes[1] / 2;       // 1600000
  const int* src = ei;
  const int* dst = ei + E;

  auto align = [](size_t v) { return (v + 255) & ~(size_t)255; };
  char* ws = (char*)d_ws;
  float* h  = (float*)ws;   ws += align((size_t)N * D * 4);
  ushort* xlh = (ushort*)ws; ws += align((size_t)N * D * 2);
  float* xr = (float*)ws;   ws += align((size_t)N * D * 4);
  int* cursor = (int*)ws;   ws += align((size_t)N * 4);
  int* ssrc   = (int*)ws;   ws += align(((size_t)N * BK + 16) * 4);

  int tblk = (N + 63) / 64;

  // CSR build: zero cursors (async memset), scatter into uninitialized buckets
  hipMemsetAsync(cursor, 0, (size_t)N * 4, stream);
  k_scatter<<<2048, 256, 0, stream>>>(src, dst, cursor, ssrc, E, N);

  // encoder
  k_encoder<<<tblk, 256, 0, stream>>>(x, W_enc, b_enc, h, N);

  for (int l = 0; l < 3; ++l) {
    k_layer_gemm<<<tblk, 256, 0, stream>>>(h, Wl + l * D * D, bl + l * D,
                                           Wr + l * D * D, br + l * D, xlh, xr, N);
    float* out = (l == 2) ? (float*)d_out : h;
    k_edge_layer<<<2048, 256, 0, stream>>>((const __half*)xlh, xr, cursor, ssrc,
                                           att + l * 64, obias + l * 64,
                                           gamma + l * 64, beta + l * 64, out, N);
  }
}